// Round 17
// baseline (4216.772 us; speedup 1.0000x reference)
//
#include <hip/hip_runtime.h>

#define BDIM 64
#define TDIM 1024
#define DDIM 256
#define HDIM 512
#define RING 8

typedef unsigned short ushort_t;
typedef unsigned int uint32;
typedef unsigned long long ull;
typedef __attribute__((ext_vector_type(8))) short short8;
typedef __attribute__((ext_vector_type(4))) float f32x4;

__device__ __forceinline__ ushort_t f2bf(float f) {
  union { float f; uint32 u; } v; v.f = f;
  uint32 u = v.u;
  return (ushort_t)((u + 0x7fffu + ((u >> 16) & 1u)) >> 16);
}

__device__ __forceinline__ short8 pack8(float4 a, float4 b) {
  short8 s;
  s[0] = (short)f2bf(a.x); s[1] = (short)f2bf(a.y);
  s[2] = (short)f2bf(a.z); s[3] = (short)f2bf(a.w);
  s[4] = (short)f2bf(b.x); s[5] = (short)f2bf(b.y);
  s[6] = (short)f2bf(b.z); s[7] = (short)f2bf(b.w);
  return s;
}

__device__ __forceinline__ ull pack4bf(f32x4 v) {
  return (ull)f2bf(v[0]) | ((ull)f2bf(v[1]) << 16)
       | ((ull)f2bf(v[2]) << 32) | ((ull)f2bf(v[3]) << 48);
}

__device__ __forceinline__ float sigm(float x) { return 1.0f / (1.0f + __expf(-x)); }
__device__ __forceinline__ float tanh_fast(float x) { return 1.0f - 2.0f / (__expf(2.0f * x) + 1.0f); }

__device__ __forceinline__ uint32 ld_sc1(uint32* p) {
  return __hip_atomic_load(p, __ATOMIC_RELAXED, __HIP_MEMORY_SCOPE_AGENT);
}
__device__ __forceinline__ void st_sc1(uint32* p, uint32 v) {
  __hip_atomic_store(p, v, __ATOMIC_RELAXED, __HIP_MEMORY_SCOPE_AGENT);
}
__device__ __forceinline__ void st_sc1_u64(ull* p, ull v) {
  __hip_atomic_store(p, v, __ATOMIC_RELAXED, __HIP_MEMORY_SCOPE_AGENT);
}
__device__ __forceinline__ ull ld_sc1_u64(const ull* p) {
  return __hip_atomic_load((ull*)p, __ATOMIC_RELAXED, __HIP_MEMORY_SCOPE_AGENT);
}

// nt load: bypasses vector L1 (non-temporal) -> reads XCD-shared L2. No inv needed.
__device__ __forceinline__ uint32 ld_nt(const uint32* p) {
  uint32 v;
  asm volatile("global_load_dword %0, %1, off nt\n\ts_waitcnt vmcnt(0)"
               : "=v"(v) : "v"(p) : "memory");
  return v;
}

__device__ __forceinline__ void wave_poll_sc1(uint32* fl, uint32 tgt) {
  int it = 0;
  for (;;) {
    uint32 v = ld_sc1(fl);
    if (__all((int)(v >= tgt))) break;
    __builtin_amdgcn_s_sleep(1);
    if (++it > 60000) break;   // bounded: wrong beats hang
  }
  asm volatile("" ::: "memory");
}
__device__ __forceinline__ void wave_poll_nt(const uint32* fl, uint32 tgt) {
  int it = 0;
  for (;;) {
    uint32 v = ld_nt(fl);
    if (__all((int)(v >= tgt))) break;
    if (++it > 120000) break;
  }
  asm volatile("" ::: "memory");
}

// ---- fragment-major LDS layout (conflict-free MFMA reads, r10/r14-proven) ----
__device__ __forceinline__ int frag_off(int row, int kf, int lg) {   // ushort units
  return kf * 512 + (((lg * 16 + row) ^ (kf & 7)) << 3);
}

// ---- r14 lane-permuted staging: conflict-free b64 writes, coalesced loads ----
__device__ __forceinline__ void ds_stage(ushort_t* dst, int tid, const ull* v) {
  const int s = tid & 15, h = (tid >> 4) & 3, wvq = tid >> 6;
#pragma unroll
  for (int q = 0; q < 8; ++q) {
    const int row = wvq * 4 + (q & 3);
    const int kf  = ((q >> 2) << 3) | ((s >> 1) & 7);
    *(ull*)&dst[frag_off(row, kf, h) + (s & 1) * 4] = v[q];
  }
}

__device__ __forceinline__ void load_sc1_8(const ull* src, int tid, ull* v) {
  const int s = tid & 15, h = (tid >> 4) & 3, wvq = tid >> 6;
#pragma unroll
  for (int q = 0; q < 8; ++q) {
    const int row = wvq * 4 + (q & 3);
    const int kf  = ((q >> 2) << 3) | ((s >> 1) & 7);
    v[q] = ld_sc1_u64(src + row * 128 + kf * 8 + h * 2 + (s & 1));
  }
}

// nt variant: same permutation. Per-thread base + constant byte offsets
// (q&3)*1024 + (q>>2)*512; all 8 issued, one waitcnt.
__device__ __forceinline__ void load_nt_8(const ull* src, int tid, ull* v) {
  const int s = tid & 15, h = (tid >> 4) & 3, wvq = tid >> 6;
  const ull* base = src + wvq * 512 + ((s >> 1) & 7) * 8 + h * 2 + (s & 1);
  asm volatile(
      "global_load_dwordx2 %0, %8, off nt\n\t"
      "global_load_dwordx2 %1, %8, off offset:1024 nt\n\t"
      "global_load_dwordx2 %2, %8, off offset:2048 nt\n\t"
      "global_load_dwordx2 %3, %8, off offset:3072 nt\n\t"
      "global_load_dwordx2 %4, %8, off offset:512 nt\n\t"
      "global_load_dwordx2 %5, %8, off offset:1536 nt\n\t"
      "global_load_dwordx2 %6, %8, off offset:2560 nt\n\t"
      "global_load_dwordx2 %7, %8, off offset:3584 nt\n\t"
      "s_waitcnt vmcnt(0)"
      : "=&v"(v[0]), "=&v"(v[1]), "=&v"(v[2]), "=&v"(v[3]),
        "=&v"(v[4]), "=&v"(v[5]), "=&v"(v[6]), "=&v"(v[7])
      : "v"(base) : "memory");
}

__global__ void __launch_bounds__(256, 1)
lstm_fused(const float* __restrict__ x,
           const float* __restrict__ w_ih0, const float* __restrict__ w_hh0,
           const float* __restrict__ b0,
           const float* __restrict__ w_ih1, const float* __restrict__ w_hh1,
           const float* __restrict__ b1,
           float* __restrict__ out,
           uint32* cnt0F, uint32* cnt1F, uint32* consF,
           uint32* h0F, uint32* h1F, uint32* voteWs, uint32* probe,
           ushort_t* ring, ushort_t* h1buf, ushort_t* h0loc, ushort_t* h1loc)
{
  const int b     = (int)blockIdx.x;
  const int g     = b & 7;
  const int layer = g >> 2;
  const int bt    = g & 3;
  const int ct    = b >> 3;
  const int tid   = (int)threadIdx.x;
  const int wv    = tid >> 6;
  const int lane  = tid & 63;
  const int lr    = lane & 15;
  const int lg    = lane >> 4;

  __shared__ __align__(16) ushort_t Is[16 * 512];   // fragment-major
  __shared__ __align__(16) ushort_t Hs[16 * 512];   // fragment-major
  __shared__ float gates[4][16][16];
  __shared__ int fastLds;

  uint32* grpXcdMask = voteWs;        // [8]
  uint32* grpRep     = voteWs + 8;    // [8]
  uint32* grpBad     = voteWs + 16;   // [8]
  uint32* cA         = voteWs + 24;
  uint32* cB         = voteWs + 25;
  uint32* xcdAll     = voteWs + 26;
  uint32* scratch    = voteWs + 31;

  // ---------- one-time: adversarial nt-coherence probe + XCD vote ----------
  if (tid == 0) {
    uint32 xcd;
    asm volatile("s_getreg_b32 %0, hwreg(HW_REG_XCC_ID, 0, 4)" : "=s"(xcd));
    xcd &= 15u;
    const int partner = ((((b >> 3) + 1) & 31) << 3) | g;   // same group, next ct
    // Phase A: prime partner slot (if nt allocates L1, this caches the STALE value)
    uint32 prime = ld_nt(probe + partner);
    if (prime == 0x5A5A5A5Au) st_sc1(scratch, 1u);          // keep live
    __hip_atomic_fetch_or(grpXcdMask + g, 1u << (xcd & 31u), __ATOMIC_RELAXED, __HIP_MEMORY_SCOPE_AGENT);
    __hip_atomic_fetch_or(xcdAll, 1u << (xcd & 31u), __ATOMIC_RELAXED, __HIP_MEMORY_SCOPE_AGENT);
    __hip_atomic_fetch_add(cA, 1u, __ATOMIC_RELAXED, __HIP_MEMORY_SCOPE_AGENT);
    int it = 0;
    while (ld_sc1(cA) < 256u) { __builtin_amdgcn_s_sleep(8); if (++it > 5000000) break; }
    // Phase B: publish own marker via the fast-path STORE mechanism
    *(volatile uint32*)(probe + b) = 0xA5000000u | (uint32)b;
    asm volatile("s_waitcnt vmcnt(0)" ::: "memory");
    __hip_atomic_fetch_add(cB, 1u, __ATOMIC_RELAXED, __HIP_MEMORY_SCOPE_AGENT);
    it = 0;
    while (ld_sc1(cB) < 256u) { __builtin_amdgcn_s_sleep(8); if (++it > 5000000) break; }
    // Phase C: nt-poll partner marker (fails if nt can serve stale L1)
    int ok = 0;
    const uint32 expect = 0xA5000000u | (uint32)partner;
    for (int k = 0; k < 6000 && !ok; ++k) {
      if (ld_nt(probe + partner) == expect) ok = 1;
    }
    if (!ok) __hip_atomic_fetch_or(grpBad + g, 1u, __ATOMIC_RELAXED, __HIP_MEMORY_SCOPE_AGENT);
    __hip_atomic_fetch_add(grpRep + g, 1u, __ATOMIC_RELAXED, __HIP_MEMORY_SCOPE_AGENT);
    it = 0;
    while (ld_sc1(grpRep + g) < 32u) { __builtin_amdgcn_s_sleep(8); if (++it > 5000000) break; }
    uint32 bad = ld_sc1(grpBad + g);
    uint32 gm  = ld_sc1(grpXcdMask + g);
    uint32 am  = ld_sc1(xcdAll);
    fastLds = (bad == 0u && __popc(gm) == 1 && __popc(am) >= 2) ? 1 : 0;
  }

  const int NI  = layer ? 16 : 8;
  const int Din = layer ? HDIM : DDIM;
  const float* wih = layer ? w_ih1 : w_ih0;
  const float* whh = layer ? w_hh1 : w_hh0;
  const float* bb  = layer ? b1 : b0;
  const int grow = wv * HDIM + ct * 16 + lr;

  short8 wf[32];
#pragma unroll
  for (int kf = 0; kf < 32; ++kf) wf[kf] = (short8)((short)0);
#pragma unroll
  for (int kf = 0; kf < 32; ++kf) {
    if (kf < NI + 16) {
      const float* src;
      if (kf < NI) src = wih + (size_t)grow * Din + (size_t)kf * 32 + lg * 8;
      else         src = whh + (size_t)grow * HDIM + (size_t)(kf - NI) * 32 + lg * 8;
      float4 a = *(const float4*)(src);
      float4 bq = *(const float4*)(src + 4);
      wf[kf] = pack8(a, bq);
    }
  }
  const float bias = bb[grow];

  __syncthreads();
  const bool fast = (bool)fastLds;

  const ull* ring_u  = (const ull*)ring;
  const ull* h1buf_u = (const ull*)h1buf;
  ull* hloc_u = (ull*)(layer ? h1loc : h0loc) + (size_t)bt * 4096;   // [2 parity][2048]
  uint32* hFl = (layer ? h1F : h0F) + bt * 32;                        // [32]

  float c4[4] = {0.f, 0.f, 0.f, 0.f};     // wave0: 4 cell states
  float4 xp0, xp1, xp2, xp3;
  const int xr = tid >> 4;
  const int xcb = tid & 15;

  if (layer == 0) {
    const float4* xv = (const float4*)(x + (size_t)(bt * 16 + xr) * (TDIM * DDIM) + xcb * 16);
    xp0 = xv[0]; xp1 = xv[1]; xp2 = xv[2]; xp3 = xv[3];
  }

  for (int t = 0; t < TDIM; ++t) {
    // ---- P1: polls (one wave per flag set — r14 structure) ----
    if (layer == 0) {
      if (wv == 0) {
        if (fast) {
          if (t > 0) {   // deferred ring flag: wave0's prior ring stores drained here
            asm volatile("s_waitcnt vmcnt(0)" ::: "memory");
            if (lane == 0) st_sc1(cnt0F + bt * 32 + ct, (uint32)t);
          }
          if (t > 0) wave_poll_nt(hFl + (lane & 31), (uint32)t);
        } else {
          if (t > 0) wave_poll_sc1(cnt0F + bt * 32 + (lane & 31), (uint32)t);
        }
      } else if (wv == 1) {
        if (t >= RING) wave_poll_sc1(consF + bt * 32 + (lane & 31), (uint32)(t - RING + 1));
      }
    } else {
      if (wv == 0) {
        if (t > 0) {
          if (fast) wave_poll_nt(hFl + (lane & 31), (uint32)t);
          else      wave_poll_sc1(cnt1F + bt * 32 + (lane & 31), (uint32)t);
        }
      } else if (wv == 1) {
        wave_poll_sc1(cnt0F + bt * 32 + (lane & 31), (uint32)(t + 1));   // ring[t] ready
      }
    }
    __syncthreads();

    // ---- P2/P3: stage inputs ----
    if (layer == 0) {
      {
        const int c0 = xcb * 16;
        *(short8*)&Is[frag_off(xr, c0 >> 5, (c0 >> 3) & 3)] = pack8(xp0, xp1);
        const int c1 = c0 + 8;
        *(short8*)&Is[frag_off(xr, c1 >> 5, (c1 >> 3) & 3)] = pack8(xp2, xp3);
      }
      if (t > 0) {
        ull hv[8];
        if (fast) load_nt_8(hloc_u + (size_t)((t - 1) & 1) * 2048, tid, hv);
        else      load_sc1_8(ring_u + (size_t)((t - 1) & (RING - 1)) * 8192 + (size_t)bt * 2048, tid, hv);
        ds_stage(Hs, tid, hv);
      }
    } else {
      ull rv[8], hv[8];
      load_sc1_8(ring_u + (size_t)(t & (RING - 1)) * 8192 + (size_t)bt * 2048, tid, rv);
      if (t > 0) {
        if (fast) load_nt_8(hloc_u + (size_t)((t - 1) & 1) * 2048, tid, hv);
        else      load_sc1_8(h1buf_u + (size_t)((t - 1) & 1) * 8192 + (size_t)bt * 2048, tid, hv);
      }
      ds_stage(Is, tid, rv);
      if (t > 0) ds_stage(Hs, tid, hv);
    }
    __syncthreads();
    if (layer == 1 && tid == 0)
      st_sc1(consF + bt * 32 + ct, (uint32)(t + 1));   // ring slot consumed

    // ---- P5: MFMA (conflict-free fragment reads) ----
    f32x4 acc0 = {0.f, 0.f, 0.f, 0.f}, acc1 = {0.f, 0.f, 0.f, 0.f};
#pragma unroll
    for (int kf = 0; kf < 16; ++kf) {
      if (kf < NI) {
        const short8 af = *(const short8*)&Is[frag_off(lr, kf, lg)];
        if (kf & 1) acc1 = __builtin_amdgcn_mfma_f32_16x16x32_bf16(af, wf[kf], acc1, 0, 0, 0);
        else        acc0 = __builtin_amdgcn_mfma_f32_16x16x32_bf16(af, wf[kf], acc0, 0, 0, 0);
      }
    }
    if (t > 0) {
#pragma unroll
      for (int kf = 0; kf < 16; ++kf) {
        const short8 af = *(const short8*)&Hs[frag_off(lr, kf, lg)];
        if (kf & 1) acc1 = __builtin_amdgcn_mfma_f32_16x16x32_bf16(af, wf[NI + kf], acc1, 0, 0, 0);
        else        acc0 = __builtin_amdgcn_mfma_f32_16x16x32_bf16(af, wf[NI + kf], acc0, 0, 0, 0);
      }
    }
#pragma unroll
    for (int i = 0; i < 4; ++i) {
      float v = acc0[i] + acc1[i] + bias;
      float a = (wv < 3) ? sigm(v) : tanh_fast(v);
      gates[wv][lg * 4 + i][lr] = a;
    }
    __syncthreads();

    // ---- P6/P7: pointwise (wave0) + publish; others prefetch x ----
    if (layer == 0 && wv != 0 && t + 1 < TDIM) {
      const float4* xv = (const float4*)(x + (size_t)(bt * 16 + xr) * (TDIM * DDIM)
                                           + (size_t)(t + 1) * DDIM + xcb * 16);
      xp0 = xv[0]; xp1 = xv[1]; xp2 = xv[2]; xp3 = xv[3];
    }
    if (wv == 0) {
      const int r  = lane >> 2;
      const int cg = lane & 3;
      f32x4 gi = *(const f32x4*)&gates[0][r][cg * 4];
      f32x4 gf = *(const f32x4*)&gates[1][r][cg * 4];
      f32x4 go = *(const f32x4*)&gates[2][r][cg * 4];
      f32x4 gg = *(const f32x4*)&gates[3][r][cg * 4];
      f32x4 nh4, nc4;
#pragma unroll
      for (int k = 0; k < 4; ++k) {
        float nc = gf[k] * c4[k] + gi[k] * gg[k];
        float nh = go[k] * tanh_fast(nc);     // h uses UNCLIPPED c
        nc = fminf(fmaxf(nc, -50.f), 50.f);
        nh = fminf(fmaxf(nh, -50.f), 50.f);
        c4[k] = nc; nh4[k] = nh; nc4[k] = nc;
      }
      const ull hv = pack4bf(nh4);
      if (fast) {
        // local (XCD-L2) publish: plain store -> vmcnt -> plain flag
        *(volatile ull*)(hloc_u + (size_t)(t & 1) * 2048 + r * 128 + ct * 4 + cg) = hv;
        asm volatile("s_waitcnt vmcnt(0)" ::: "memory");
        if (lane == 0) *(volatile uint32*)(hFl + ct) = (uint32)(t + 1);
        if (layer == 0) {   // ring copy for layer1: sc1, flag deferred to next P1
          st_sc1_u64((ull*)(ring_u + (size_t)(t & (RING - 1)) * 8192
                            + (size_t)(bt * 16 + r) * 128 + ct * 4 + cg), hv);
        }
      } else {
        ull* dst;
        if (layer == 0)
          dst = (ull*)(ring_u + (size_t)(t & (RING - 1)) * 8192
                       + (size_t)(bt * 16 + r) * 128 + ct * 4 + cg);
        else
          dst = (ull*)(h1buf_u + (size_t)(t & 1) * 8192
                       + (size_t)(bt * 16 + r) * 128 + ct * 4 + cg);
        st_sc1_u64(dst, hv);
        asm volatile("s_waitcnt vmcnt(0)" ::: "memory");
        if (lane == 0) st_sc1((layer == 0 ? cnt0F : cnt1F) + bt * 32 + ct, (uint32)(t + 1));
      }
      if (layer == 1)
        *(f32x4*)&out[(size_t)(bt * 16 + r) * (TDIM * HDIM) + (size_t)t * HDIM + ct * 16 + cg * 4] = nh4;
      if (t == TDIM - 1) {
        const size_t OH = (size_t)BDIM * TDIM * HDIM;
        const size_t OC = OH + 2 * (size_t)BDIM * HDIM;
        *(f32x4*)&out[OH + (size_t)layer * BDIM * HDIM + (size_t)(bt * 16 + r) * HDIM + ct * 16 + cg * 4] = nh4;
        *(f32x4*)&out[OC + (size_t)layer * BDIM * HDIM + (size_t)(bt * 16 + r) * HDIM + ct * 16 + cg * 4] = nc4;
      }
      if (layer == 0 && t + 1 < TDIM) {
        const float4* xv = (const float4*)(x + (size_t)(bt * 16 + xr) * (TDIM * DDIM)
                                             + (size_t)(t + 1) * DDIM + xcb * 16);
        xp0 = xv[0]; xp1 = xv[1]; xp2 = xv[2]; xp3 = xv[3];
      }
    }
  }

  // epilogue (fast layer0): release final ring slots to layer1
  if (fast && layer == 0 && wv == 0) {
    asm volatile("s_waitcnt vmcnt(0)" ::: "memory");
    if (lane == 0) st_sc1(cnt0F + bt * 32 + ct, (uint32)TDIM);
  }
}

extern "C" void kernel_launch(void* const* d_in, const int* in_sizes, int n_in,
                              void* d_out, int out_size, void* d_ws, size_t ws_size,
                              hipStream_t stream) {
  (void)in_sizes; (void)n_in; (void)out_size; (void)ws_size;
  const float* x     = (const float*)d_in[0];
  const float* w_ih0 = (const float*)d_in[1];
  const float* w_hh0 = (const float*)d_in[2];
  const float* b0    = (const float*)d_in[3];
  const float* w_ih1 = (const float*)d_in[4];
  const float* w_hh1 = (const float*)d_in[5];
  const float* b1    = (const float*)d_in[6];
  float* out = (float*)d_out;

  char* ws = (char*)d_ws;
  uint32* cnt0F  = (uint32*)(ws + 0);      // [4][32]
  uint32* cnt1F  = (uint32*)(ws + 512);    // [4][32]
  uint32* consF  = (uint32*)(ws + 1024);   // [4][32]
  uint32* h0F    = (uint32*)(ws + 1536);   // [4][32] local-flag (plain/nt)
  uint32* h1F    = (uint32*)(ws + 2048);   // [4][32]
  uint32* voteWs = (uint32*)(ws + 2560);
  uint32* probe  = (uint32*)(ws + 3072);   // [256]
  ushort_t* ring  = (ushort_t*)(ws + 8192);                         // [8][64][512] (512KB)
  ushort_t* h1buf = (ushort_t*)(ws + 8192 + 524288);                // [2][64][512] (128KB)
  ushort_t* h0loc = (ushort_t*)(ws + 8192 + 524288 + 131072);       // [4][2][16][512] (128KB)
  ushort_t* h1loc = (ushort_t*)(ws + 8192 + 524288 + 262144);       // [4][2][16][512] (128KB)

  hipMemsetAsync(ws, 0, 8192, stream);
  lstm_fused<<<dim3(256), dim3(256), 0, stream>>>(
      x, w_ih0, w_hh0, b0, w_ih1, w_hh1, b1, out,
      cnt0F, cnt1F, consF, h0F, h1F, voteWs, probe,
      ring, h1buf, h0loc, h1loc);
}

// Round 19
// 2612.324 us; speedup vs baseline: 1.6142x; 1.6142x over previous
//
#include <hip/hip_runtime.h>

#define BDIM 64
#define TDIM 1024
#define DDIM 256
#define HDIM 512
#define RING 4

typedef unsigned short ushort_t;
typedef unsigned int uint32;
typedef unsigned long long ull;
typedef __attribute__((ext_vector_type(8))) short short8;
typedef __attribute__((ext_vector_type(4))) float f32x4;
typedef __attribute__((ext_vector_type(4))) uint32 u32x4;

__device__ __forceinline__ ushort_t f2bf(float f) {
  union { float f; uint32 u; } v; v.f = f;
  uint32 u = v.u;
  return (ushort_t)((u + 0x7fffu + ((u >> 16) & 1u)) >> 16);
}

__device__ __forceinline__ short8 pack8(float4 a, float4 b) {
  short8 s;
  s[0] = (short)f2bf(a.x); s[1] = (short)f2bf(a.y);
  s[2] = (short)f2bf(a.z); s[3] = (short)f2bf(a.w);
  s[4] = (short)f2bf(b.x); s[5] = (short)f2bf(b.y);
  s[6] = (short)f2bf(b.z); s[7] = (short)f2bf(b.w);
  return s;
}

__device__ __forceinline__ ull pack4bf(f32x4 v) {
  return (ull)f2bf(v[0]) | ((ull)f2bf(v[1]) << 16)
       | ((ull)f2bf(v[2]) << 32) | ((ull)f2bf(v[3]) << 48);
}

__device__ __forceinline__ float sigm(float x) { return 1.0f / (1.0f + __expf(-x)); }
__device__ __forceinline__ float tanh_fast(float x) { return 1.0f - 2.0f / (__expf(2.0f * x) + 1.0f); }

__device__ __forceinline__ uint32 ld_sc1(uint32* p) {
  return __hip_atomic_load(p, __ATOMIC_RELAXED, __HIP_MEMORY_SCOPE_AGENT);
}
__device__ __forceinline__ void st_sc1(uint32* p, uint32 v) {
  __hip_atomic_store(p, v, __ATOMIC_RELAXED, __HIP_MEMORY_SCOPE_AGENT);
}

__device__ __forceinline__ void wave_poll_sc1(uint32* fl, uint32 tgt) {
  int it = 0;
  for (;;) {
    uint32 v = ld_sc1(fl);
    if (__all((int)(v >= tgt))) break;
    __builtin_amdgcn_s_sleep(1);
    if (++it > 60000) break;   // bounded: wrong beats hang
  }
  asm volatile("" ::: "memory");
}

// ---- fragment-major LDS layout (conflict-free MFMA reads, r10/r14-proven) ----
__device__ __forceinline__ int frag_off(int row, int kf, int lg) {   // ushort units
  return kf * 512 + (((lg * 16 + row) ^ (kf & 7)) << 3);
}

// ---- r14 lane-permuted staging map: conflict-free b64 LDS writes ----
__device__ __forceinline__ void ds_stage(ushort_t* dst, int tid, const ull* v) {
  const int s = tid & 15, h = (tid >> 4) & 3, wvq = tid >> 6;
#pragma unroll
  for (int q = 0; q < 8; ++q) {
    const int row = wvq * 4 + (q & 3);
    const int kf  = ((q >> 2) << 3) | ((s >> 1) & 7);
    *(ull*)&dst[frag_off(row, kf, h) + (s & 1) * 4] = v[q];
  }
}

// ---- tag-fused tile load: 16B chunks [h:8B][tag:4B][pad:4B], spin per-thread ----
// chunk(row, c) at byte row*2048 + c*16, c = kf*8 + h*2 + e2 (r14 index space).
// Per instruction the wave covers a contiguous 1KB window -> fully coalesced.
// Global offsets are 13-bit signed (<=4095): use two bases, offsets 0..3072.
__device__ __forceinline__ void load_tagged_8(const char* buf, int tid, uint32 expect, ull* v) {
  const int s = tid & 15, h = (tid >> 4) & 3, wvq = tid >> 6;
  const char* base  = buf + (size_t)(wvq * 4) * 2048
                    + (size_t)(((((s >> 1) & 7) * 8) + h * 2 + (s & 1)) * 16);
  const char* base2 = base + 4096;
  u32x4 c0, c1, c2, c3, c4v, c5, c6, c7;
  int it = 0;
  for (;;) {
    asm volatile(
        "global_load_dwordx4 %0, %8, off sc0 sc1\n\t"
        "global_load_dwordx4 %1, %8, off offset:1024 sc0 sc1\n\t"
        "global_load_dwordx4 %2, %8, off offset:2048 sc0 sc1\n\t"
        "global_load_dwordx4 %3, %8, off offset:3072 sc0 sc1\n\t"
        "global_load_dwordx4 %4, %9, off sc0 sc1\n\t"
        "global_load_dwordx4 %5, %9, off offset:1024 sc0 sc1\n\t"
        "global_load_dwordx4 %6, %9, off offset:2048 sc0 sc1\n\t"
        "global_load_dwordx4 %7, %9, off offset:3072 sc0 sc1\n\t"
        "s_waitcnt vmcnt(0)"
        : "=&v"(c0), "=&v"(c1), "=&v"(c2), "=&v"(c3),
          "=&v"(c4v), "=&v"(c5), "=&v"(c6), "=&v"(c7)
        : "v"(base), "v"(base2) : "memory");
    bool ok = (c0.z == expect) & (c1.z == expect) & (c2.z == expect) & (c3.z == expect)
            & (c4v.z == expect) & (c5.z == expect) & (c6.z == expect) & (c7.z == expect);
    if (ok) break;
    if (++it > 30000) break;   // bounded: wrong beats hang
  }
  // q ordering: base covers rows wvq*4 + {0,1,2,3} at offset 0..3072? No:
  // offsets step 1024 = half-row; row stride is 2048. base+q*1024 for q=0..3
  // = rows wvq*4+0,+0.5.. — careful: map back to r14's q indexing:
  // r14 q: row=wvq*4+(q&3), kf_hi=(q>>2). Chunk byte = row*2048 + (kf_hi*64 + c_lo)*16
  //   = row*2048 + kf_hi*1024 + c_lo*16.
  // base already includes c_lo*16; so q-th load addr = base + (q&3)*2048 + (q>>2)*1024.
  // The 8 offsets from {base,base2} = {0,1024,2048,3072,4096,5120,6144,7168} cover
  // exactly {(q&3)*2048+(q>>2)*1024}: 0->q0,1024->q4,2048->q1,3072->q5,
  // 4096->q2,5120->q6,6144->q3,7168->q7.
  v[0] = ((ull)c0.y << 32) | c0.x;   v[4] = ((ull)c1.y << 32) | c1.x;
  v[1] = ((ull)c2.y << 32) | c2.x;   v[5] = ((ull)c3.y << 32) | c3.x;
  v[2] = ((ull)c4v.y << 32) | c4v.x; v[6] = ((ull)c5.y << 32) | c5.x;
  v[3] = ((ull)c6.y << 32) | c6.x;   v[7] = ((ull)c7.y << 32) | c7.x;
}

#define BT_BYTES   32768            // 16 rows x 128 chunks x 16B
#define SLOT_BYTES (4 * BT_BYTES)   // 4 bt tiles

__global__ void __launch_bounds__(256, 1)
lstm_fused(const float* __restrict__ x,
           const float* __restrict__ w_ih0, const float* __restrict__ w_hh0,
           const float* __restrict__ b0,
           const float* __restrict__ w_ih1, const float* __restrict__ w_hh1,
           const float* __restrict__ b1,
           float* __restrict__ out,
           uint32* consF, char* ringT, char* h1T)
{
  const int b     = (int)blockIdx.x;
  const int g     = b & 7;
  const int layer = g >> 2;
  const int bt    = g & 3;
  const int ct    = b >> 3;
  const int tid   = (int)threadIdx.x;
  const int wv    = tid >> 6;
  const int lane  = tid & 63;
  const int lr    = lane & 15;
  const int lg    = lane >> 4;

  __shared__ __align__(16) ushort_t Is[16 * 512];   // fragment-major
  __shared__ __align__(16) ushort_t Hs[16 * 512];   // fragment-major
  __shared__ __align__(16) float gates[4][16][16];

  const int NI  = layer ? 16 : 8;
  const int Din = layer ? HDIM : DDIM;
  const float* wih = layer ? w_ih1 : w_ih0;
  const float* whh = layer ? w_hh1 : w_hh0;
  const float* bb  = layer ? b1 : b0;
  const int grow = wv * HDIM + ct * 16 + lr;

  short8 wf[32];
#pragma unroll
  for (int kf = 0; kf < 32; ++kf) wf[kf] = (short8)((short)0);
#pragma unroll
  for (int kf = 0; kf < 32; ++kf) {
    if (kf < NI + 16) {
      const float* src;
      if (kf < NI) src = wih + (size_t)grow * Din + (size_t)kf * 32 + lg * 8;
      else         src = whh + (size_t)grow * HDIM + (size_t)(kf - NI) * 32 + lg * 8;
      float4 a = *(const float4*)(src);
      float4 bq = *(const float4*)(src + 4);
      wf[kf] = pack8(a, bq);
    }
  }
  const float bias = bb[grow];

  float c4[4] = {0.f, 0.f, 0.f, 0.f};     // wave0: 4 cell states
  float4 xp0, xp1, xp2, xp3;
  const int xr = tid >> 4;
  const int xcb = tid & 15;

  if (layer == 0) {
    const float4* xv = (const float4*)(x + (size_t)(bt * 16 + xr) * (TDIM * DDIM) + xcb * 16);
    xp0 = xv[0]; xp1 = xv[1]; xp2 = xv[2]; xp3 = xv[3];
  }

  for (int t = 0; t < TDIM; ++t) {
    // ---- P1: only layer0 wave1 polls ring back-pressure (off-critical) ----
    if (layer == 0 && wv == 1 && t >= RING)
      wave_poll_sc1(consF + bt * 32 + (lane & 31), (uint32)(t - RING + 1));

    // ---- P2/P3: tag-fused loads + stage (per-thread readiness, no flags) ----
    if (layer == 0) {
      {
        const int c0 = xcb * 16;
        *(short8*)&Is[frag_off(xr, c0 >> 5, (c0 >> 3) & 3)] = pack8(xp0, xp1);
        const int c1 = c0 + 8;
        *(short8*)&Is[frag_off(xr, c1 >> 5, (c1 >> 3) & 3)] = pack8(xp2, xp3);
      }
      if (t > 0) {
        ull hv[8];
        load_tagged_8(ringT + (size_t)((t - 1) & (RING - 1)) * SLOT_BYTES
                      + (size_t)bt * BT_BYTES, tid, (uint32)t, hv);
        ds_stage(Hs, tid, hv);
      }
    } else {
      ull rv[8], hv[8];
      load_tagged_8(ringT + (size_t)(t & (RING - 1)) * SLOT_BYTES
                    + (size_t)bt * BT_BYTES, tid, (uint32)(t + 1), rv);
      if (t > 0)
        load_tagged_8(h1T + (size_t)((t - 1) & 1) * SLOT_BYTES
                      + (size_t)bt * BT_BYTES, tid, (uint32)t, hv);
      ds_stage(Is, tid, rv);
      if (t > 0) ds_stage(Hs, tid, hv);
    }
    __syncthreads();   // B1: tiles complete
    if (layer == 1 && tid == 0)
      st_sc1(consF + bt * 32 + ct, (uint32)(t + 1));   // ring slot consumed

    // ---- P5: MFMA (conflict-free fragment reads) ----
    f32x4 acc0 = {0.f, 0.f, 0.f, 0.f}, acc1 = {0.f, 0.f, 0.f, 0.f};
#pragma unroll
    for (int kf = 0; kf < 16; ++kf) {
      if (kf < NI) {
        const short8 af = *(const short8*)&Is[frag_off(lr, kf, lg)];
        if (kf & 1) acc1 = __builtin_amdgcn_mfma_f32_16x16x32_bf16(af, wf[kf], acc1, 0, 0, 0);
        else        acc0 = __builtin_amdgcn_mfma_f32_16x16x32_bf16(af, wf[kf], acc0, 0, 0, 0);
      }
    }
    if (t > 0) {
#pragma unroll
      for (int kf = 0; kf < 16; ++kf) {
        const short8 af = *(const short8*)&Hs[frag_off(lr, kf, lg)];
        if (kf & 1) acc1 = __builtin_amdgcn_mfma_f32_16x16x32_bf16(af, wf[NI + kf], acc1, 0, 0, 0);
        else        acc0 = __builtin_amdgcn_mfma_f32_16x16x32_bf16(af, wf[NI + kf], acc0, 0, 0, 0);
      }
    }
#pragma unroll
    for (int i = 0; i < 4; ++i) {
      float v = acc0[i] + acc1[i] + bias;
      float a = (wv < 3) ? sigm(v) : tanh_fast(v);
      gates[wv][lg * 4 + i][lr] = a;
    }
    __syncthreads();   // B2: gates complete (also fences Hs/Is reuse)

    // ---- P6/P7: pointwise (wave0) + tagged publish; others prefetch x ----
    if (layer == 0 && wv != 0 && t + 1 < TDIM) {
      const float4* xv = (const float4*)(x + (size_t)(bt * 16 + xr) * (TDIM * DDIM)
                                           + (size_t)(t + 1) * DDIM + xcb * 16);
      xp0 = xv[0]; xp1 = xv[1]; xp2 = xv[2]; xp3 = xv[3];
    }
    if (wv == 0) {
      const int r  = lane >> 2;
      const int cg = lane & 3;
      f32x4 gi = *(const f32x4*)&gates[0][r][cg * 4];
      f32x4 gf = *(const f32x4*)&gates[1][r][cg * 4];
      f32x4 go = *(const f32x4*)&gates[2][r][cg * 4];
      f32x4 gg = *(const f32x4*)&gates[3][r][cg * 4];
      f32x4 nh4, nc4;
#pragma unroll
      for (int k = 0; k < 4; ++k) {
        float nc = gf[k] * c4[k] + gi[k] * gg[k];
        float nh = go[k] * tanh_fast(nc);     // h uses UNCLIPPED c
        nc = fminf(fmaxf(nc, -50.f), 50.f);
        nh = fminf(fmaxf(nh, -50.f), 50.f);
        c4[k] = nc; nh4[k] = nh; nc4[k] = nc;
      }
      const ull hv = pack4bf(nh4);
      // tagged publish: ONE 16B store, no ack, no flag. The wave's own next
      // tag-spin s_waitcnt vmcnt(0) drains it (same-address ordering safe).
      u32x4 pub;
      pub.x = (uint32)hv; pub.y = (uint32)(hv >> 32);
      pub.z = (uint32)(t + 1); pub.w = 0u;
      char* dst = (layer == 0)
          ? ringT + (size_t)(t & (RING - 1)) * SLOT_BYTES + (size_t)bt * BT_BYTES
          : h1T + (size_t)(t & 1) * SLOT_BYTES + (size_t)bt * BT_BYTES;
      dst += (size_t)r * 2048 + (size_t)(ct * 4 + cg) * 16;
      asm volatile("global_store_dwordx4 %0, %1, off sc0 sc1"
                   :: "v"(dst), "v"(pub) : "memory");
      if (layer == 1)
        *(f32x4*)&out[(size_t)(bt * 16 + r) * (TDIM * HDIM) + (size_t)t * HDIM + ct * 16 + cg * 4] = nh4;
      if (t == TDIM - 1) {
        const size_t OH = (size_t)BDIM * TDIM * HDIM;
        const size_t OC = OH + 2 * (size_t)BDIM * HDIM;
        *(f32x4*)&out[OH + (size_t)layer * BDIM * HDIM + (size_t)(bt * 16 + r) * HDIM + ct * 16 + cg * 4] = nh4;
        *(f32x4*)&out[OC + (size_t)layer * BDIM * HDIM + (size_t)(bt * 16 + r) * HDIM + ct * 16 + cg * 4] = nc4;
      }
      if (layer == 0 && t + 1 < TDIM) {
        const float4* xv = (const float4*)(x + (size_t)(bt * 16 + xr) * (TDIM * DDIM)
                                             + (size_t)(t + 1) * DDIM + xcb * 16);
        xp0 = xv[0]; xp1 = xv[1]; xp2 = xv[2]; xp3 = xv[3];
      }
    }
  }
}

extern "C" void kernel_launch(void* const* d_in, const int* in_sizes, int n_in,
                              void* d_out, int out_size, void* d_ws, size_t ws_size,
                              hipStream_t stream) {
  (void)in_sizes; (void)n_in; (void)out_size; (void)ws_size;
  const float* x     = (const float*)d_in[0];
  const float* w_ih0 = (const float*)d_in[1];
  const float* w_hh0 = (const float*)d_in[2];
  const float* b0    = (const float*)d_in[3];
  const float* w_ih1 = (const float*)d_in[4];
  const float* w_hh1 = (const float*)d_in[5];
  const float* b1    = (const float*)d_in[6];
  float* out = (float*)d_out;

  char* ws = (char*)d_ws;
  uint32* consF = (uint32*)(ws + 0);                 // [4][32]
  char* ringT = ws + 8192;                           // 4 slots x 4bt x 32KB = 512KB tagged
  char* h1T   = ws + 8192 + 4 * SLOT_BYTES;          // 2 par  x 4bt x 32KB = 256KB tagged

  // memset EVERY launch: resets tags (replay-safe) + consF
  hipMemsetAsync(ws, 0, 8192, stream);
  hipMemsetAsync(ws + 8192, 0, 6 * SLOT_BYTES, stream);
  lstm_fused<<<dim3(256), dim3(256), 0, stream>>>(
      x, w_ih0, w_hh0, b0, w_ih1, w_hh1, b1, out, consF, ringT, h1T);
}